// Round 3
// baseline (92.544 us; speedup 1.0000x reference)
//
#include <hip/hip_runtime.h>

// B=8192 all-pairs hinge ranking loss:
//   out = sum_{i,j} [ti<tj][ev_i] * relu(1 - (rj - ri)) / sum_{i,j} [ti<tj][ev_i]
// z (d_in[0]) unused.
//
// Measurement note (R2 rocprof): timed window is dominated (~80 of 84 us) by
// the harness's 268 MB d_ws poison fills at ~80% HBM peak — not kernel-
// controllable. Kernel-side budget is ~5 us, VALU-bound:
//   67.1M pairs / 64 lanes * 5 VALU * 2 cyc / 1024 SIMD / 2.4 GHz ~= 4.3 us.
// Count accumulation moved to SALU (v_cmp -> s_bcnt1/s_add) via
// __popcll(__ballot(m)) so the VALU does only cmp/sub/max/cndmask/add.
// IPT=4 keeps LDS ds_read_b128 traffic (2.6 us/CU) under the VALU time;
// IPT=2 would double LDS traffic past it (checked: 5.1 us/CU).

#define MARGIN_F 1.0f
#define B_N   8192
#define TPB   256
#define IPT   4
#define JT    256
#define GRID_X (B_N / (TPB * IPT))   // 8
#define GRID_Y (B_N / JT)            // 32
#define NBLOCKS (GRID_X * GRID_Y)    // 256

struct Ws {
    double total;
    unsigned long long cnt;
    unsigned int ticket;
    unsigned int pad;
};

__global__ __launch_bounds__(TPB) void sgr_kernel(
    const float* __restrict__ risk,
    const float* __restrict__ tim,
    const int*   __restrict__ event,
    Ws*          __restrict__ ws,
    float*       __restrict__ out)
{
    __shared__ float4 s_t4[JT / 4];
    __shared__ float4 s_r4[JT / 4];

    const int t     = threadIdx.x;
    const int jbase = blockIdx.y * JT;

    // Stage j-tile (coalesced float loads, TPB == JT).
    ((float*)s_t4)[t] = tim[jbase + t];
    ((float*)s_r4)[t] = risk[jbase + t];
    __syncthreads();

    const int ibase = blockIdx.x * (TPB * IPT);
    float ti[IPT], rip1[IPT], sum[IPT];
    #pragma unroll
    for (int k = 0; k < IPT; ++k) {
        const int i  = ibase + k * TPB + t;       // coalesced
        const bool ev = (event[i] == 1);
        ti[k]   = ev ? tim[i] : __builtin_inff(); // +inf => ti<tj never true
        rip1[k] = risk[i] + MARGIN_F;
        sum[k]  = 0.0f;
    }
    unsigned long long wave_cnt = 0ull;           // wave-uniform (SGPR)

    #pragma unroll 4
    for (int c = 0; c < JT / 4; ++c) {
        const float4 t4 = s_t4[c];   // ds_read_b128, wave-uniform broadcast
        const float4 r4 = s_r4[c];
        const float tj[4] = {t4.x, t4.y, t4.z, t4.w};
        const float rj[4] = {r4.x, r4.y, r4.z, r4.w};
        #pragma unroll
        for (int u = 0; u < 4; ++u) {
            #pragma unroll
            for (int k = 0; k < IPT; ++k) {
                const bool  m = ti[k] < tj[u];
                const float h = fmaxf(rip1[k] - rj[u], 0.0f);
                sum[k] += m ? h : 0.0f;                    // v_cndmask + v_add
                wave_cnt += __popcll(__ballot(m));         // s_bcnt1 + s_add (SALU)
            }
        }
    }

    float s = (sum[0] + sum[1]) + (sum[2] + sum[3]);
    #pragma unroll
    for (int off = 32; off > 0; off >>= 1)
        s += __shfl_down(s, off, 64);

    __shared__ float              w_s[TPB / 64];
    __shared__ unsigned long long w_c[TPB / 64];
    const int wave = t >> 6, lane = t & 63;
    if (lane == 0) { w_s[wave] = s; w_c[wave] = wave_cnt; }
    __syncthreads();

    if (t == 0) {
        const float              bs = (w_s[0] + w_s[1]) + (w_s[2] + w_s[3]);
        const unsigned long long bc = (w_c[0] + w_c[1]) + (w_c[2] + w_c[3]);
        atomicAdd(&ws->total, (double)bs);
        atomicAdd(&ws->cnt, bc);
        __threadfence();                                  // publish before ticket
        const unsigned int old = atomicAdd(&ws->ticket, 1u);
        if (old == NBLOCKS - 1) {
            // All 256 block-atomics complete & visible (each fenced before its
            // ticket increment). Re-read through atomics for coherence.
            const double             tot = atomicAdd(&ws->total, 0.0);
            const unsigned long long cc  = atomicAdd(&ws->cnt, 0ull);
            out[0] = cc ? (float)(tot / (double)cc) : 0.0f;
        }
    }
}

extern "C" void kernel_launch(void* const* d_in, const int* in_sizes, int n_in,
                              void* d_out, int out_size, void* d_ws, size_t ws_size,
                              hipStream_t stream)
{
    // setup_inputs order: z [B*D] (unused), risk [B], time [B], event [B]
    const float* risk  = (const float*)d_in[1];
    const float* tim   = (const float*)d_in[2];
    const int*   event = (const int*)d_in[3];
    float*       out   = (float*)d_out;
    Ws*          ws    = (Ws*)d_ws;

    hipMemsetAsync(ws, 0, sizeof(Ws), stream);   // zero accumulators + ticket

    dim3 grid(GRID_X, GRID_Y);
    sgr_kernel<<<grid, TPB, 0, stream>>>(risk, tim, event, ws, out);
}

// Round 4
// 85.549 us; speedup vs baseline: 1.0818x; 1.0818x over previous
//
#include <hip/hip_runtime.h>

// B=8192 all-pairs hinge ranking loss:
//   out = sum_{i,j} [ti<tj][ev_i] * relu(1 - (rj - ri)) / sum_{i,j} [ti<tj][ev_i]
// z (d_in[0]) unused.
//
// Measurement notes (R2/R3 rocprof):
//  - Timed window is dominated by the harness's 268 MB d_ws poison fills
//    (~41 us each at ~80% HBM peak, 2 per window ~= 80-85 us) — not kernel-
//    controllable. Window noise ~8 us run-to-run.
//  - Kernel-side budget ~5 us, VALU-bound:
//    67.1M pairs / 64 lanes * 5-6 VALU * 2 cyc / 1024 SIMD / 2.4 GHz.
//  - R3's __ballot/__popcll count regressed (64-bit per-lane += is 2 VALU vs
//    1 for u32; compiler can't prove wave-uniformity) — reverted to per-thread
//    u32 count (R2 config, best measured: 84.2 us).
// IPT=4 keeps LDS ds_read_b128 traffic (~2.6 us/CU) under the VALU time.

#define MARGIN_F 1.0f
#define B_N   8192
#define TPB   256
#define IPT   4
#define JT    256
#define GRID_X (B_N / (TPB * IPT))   // 8
#define GRID_Y (B_N / JT)            // 32
#define NBLOCKS (GRID_X * GRID_Y)    // 256

struct Ws {
    double total;
    unsigned int cnt;
    unsigned int ticket;
};

__global__ __launch_bounds__(TPB) void sgr_kernel(
    const float* __restrict__ risk,
    const float* __restrict__ tim,
    const int*   __restrict__ event,
    Ws*          __restrict__ ws,
    float*       __restrict__ out)
{
    __shared__ float4 s_t4[JT / 4];
    __shared__ float4 s_r4[JT / 4];

    const int t     = threadIdx.x;
    const int jbase = blockIdx.y * JT;

    // Stage j-tile (coalesced float loads, TPB == JT).
    ((float*)s_t4)[t] = tim[jbase + t];
    ((float*)s_r4)[t] = risk[jbase + t];
    __syncthreads();

    const int ibase = blockIdx.x * (TPB * IPT);
    float ti[IPT], rip1[IPT], sum[IPT];
    unsigned int cnt[IPT];
    #pragma unroll
    for (int k = 0; k < IPT; ++k) {
        const int i  = ibase + k * TPB + t;       // coalesced
        const bool ev = (event[i] == 1);
        ti[k]   = ev ? tim[i] : __builtin_inff(); // +inf => ti<tj never true
        rip1[k] = risk[i] + MARGIN_F;
        sum[k]  = 0.0f;
        cnt[k]  = 0u;
    }

    #pragma unroll 4
    for (int c = 0; c < JT / 4; ++c) {
        const float4 t4 = s_t4[c];   // ds_read_b128, wave-uniform broadcast
        const float4 r4 = s_r4[c];
        const float tj[4] = {t4.x, t4.y, t4.z, t4.w};
        const float rj[4] = {r4.x, r4.y, r4.z, r4.w};
        #pragma unroll
        for (int u = 0; u < 4; ++u) {
            #pragma unroll
            for (int k = 0; k < IPT; ++k) {
                const bool  m = ti[k] < tj[u];
                const float h = fmaxf(rip1[k] - rj[u], 0.0f);
                sum[k] += m ? h : 0.0f;     // v_cndmask + v_add
                cnt[k] += m ? 1u : 0u;      // v_add with mask — per-thread cnt <= 8192, exact
            }
        }
    }

    float        s  = (sum[0] + sum[1]) + (sum[2] + sum[3]);
    unsigned int cu = (cnt[0] + cnt[1]) + (cnt[2] + cnt[3]);

    #pragma unroll
    for (int off = 32; off > 0; off >>= 1) {
        s  += __shfl_down(s, off, 64);
        cu += __shfl_down(cu, off, 64);
    }

    __shared__ float        w_s[TPB / 64];
    __shared__ unsigned int w_c[TPB / 64];
    const int wave = t >> 6, lane = t & 63;
    if (lane == 0) { w_s[wave] = s; w_c[wave] = cu; }
    __syncthreads();

    if (t == 0) {
        const float        bs = (w_s[0] + w_s[1]) + (w_s[2] + w_s[3]);
        const unsigned int bc = (w_c[0] + w_c[1]) + (w_c[2] + w_c[3]);
        atomicAdd(&ws->total, (double)bs);
        atomicAdd(&ws->cnt, bc);
        __threadfence();                                  // publish before ticket
        const unsigned int old = atomicAdd(&ws->ticket, 1u);
        if (old == NBLOCKS - 1) {
            // All 256 block-atomics complete & visible (each fenced before its
            // ticket increment). Re-read through atomics for coherence.
            const double       tot = atomicAdd(&ws->total, 0.0);
            const unsigned int cc  = atomicAdd(&ws->cnt, 0u);
            out[0] = cc ? (float)(tot / (double)cc) : 0.0f;
        }
    }
}

extern "C" void kernel_launch(void* const* d_in, const int* in_sizes, int n_in,
                              void* d_out, int out_size, void* d_ws, size_t ws_size,
                              hipStream_t stream)
{
    // setup_inputs order: z [B*D] (unused), risk [B], time [B], event [B]
    const float* risk  = (const float*)d_in[1];
    const float* tim   = (const float*)d_in[2];
    const int*   event = (const int*)d_in[3];
    float*       out   = (float*)d_out;
    Ws*          ws    = (Ws*)d_ws;

    hipMemsetAsync(ws, 0, sizeof(Ws), stream);   // zero accumulators + ticket

    dim3 grid(GRID_X, GRID_Y);
    sgr_kernel<<<grid, TPB, 0, stream>>>(risk, tim, event, ws, out);
}